// Round 7
// baseline (819200.293 us; speedup 1.0000x reference)
//
#include <hip/hip_runtime.h>

#define SEQ   2048
#define HID   512
#define NB    32
#define NWG   256
#define NTHR  256
#define POLL_CAP 5000000

typedef __attribute__((ext_vector_type(8))) short bf16x8;
typedef __attribute__((ext_vector_type(4))) float f32x4;
typedef __attribute__((ext_vector_type(4))) unsigned u32x4;
typedef __attribute__((ext_vector_type(2))) unsigned u32x2;

__device__ __forceinline__ float sigf(float x) { return 1.0f / (1.0f + __expf(-x)); }
__device__ __forceinline__ float tanhf_fast(float x) {
    float e = __expf(2.0f * x);
    return (e - 1.0f) / (e + 1.0f);
}
__device__ __forceinline__ short f2bf(float f) {
    unsigned u = __float_as_uint(f);
    unsigned r = (u + 0x7FFFu + ((u >> 16) & 1u)) >> 16;
    return (short)r;
}
__device__ __forceinline__ float bf2f(unsigned short s) {
    return __uint_as_float(((unsigned)s) << 16);
}
__device__ __forceinline__ unsigned pack2(float a, float b) {
    return (unsigned)(unsigned short)f2bf(a) | ((unsigned)(unsigned short)f2bf(b) << 16);
}
__device__ __forceinline__ bf16x8 cvt8(float4 a, float4 b) {
    bf16x8 r;
    r[0] = f2bf(a.x); r[1] = f2bf(a.y); r[2] = f2bf(a.z); r[3] = f2bf(a.w);
    r[4] = f2bf(b.x); r[5] = f2bf(b.y); r[6] = f2bf(b.z); r[7] = f2bf(b.w);
    return r;
}

// sc0 load: bypass L1, served by this XCD's L2 (fast, XCD-coherent).
__device__ __forceinline__ u32x4 ld_sc0x4(const unsigned* p) {
    u32x4 v;
    asm volatile("global_load_dwordx4 %0, %1, off sc0\n\ts_waitcnt vmcnt(0)"
                 : "=&v"(v) : "v"(p) : "memory");
    return v;
}

// XCD-replicated persistent LSTM.
// 8 replicas (one per physical XCD, via s_getreg HW_REG_XCC_ID), each of 32 WGs,
// each replica computes the FULL 2-layer recurrence redundantly. All cross-WG
// traffic (h state u32-packed bf16 pairs, arrival flags) stays in the XCD's L2:
// sc0 stores (write-through, ACKed by L2 at vmcnt(0)) + sc0 loads (L1-bypass).
// Per WG: 32 hidden cols x 4 gates = 128 gate rows; weights resident in VGPRs
// (bf16, 256 VGPR/lane); 4 waves x 8 cols; MFMA 16x16x32 (proven layout:
// A row = lane&15, k-slot = (lane>>4)*8+q; C col = lane&15, row = (lane>>4)*4+reg).
__global__ __launch_bounds__(NTHR, 1) void lstm_xcd(
    const int*   __restrict__ tokens, const float* __restrict__ emb,
    const float* __restrict__ w_ih,   const float* __restrict__ w_hh,
    const float* __restrict__ b_ih,   const float* __restrict__ b_hh,
    const float* __restrict__ fc_w,   const float* __restrict__ fc_b,
    float* __restrict__ out, unsigned* __restrict__ ws)
{
    __shared__ __attribute__((aligned(16))) short inp[NB][520];     // one 512-wide input, +8 pad
    __shared__ __attribute__((aligned(16))) float gbuf[4][NB][36];  // [gate][batch][col+pad]
    __shared__ int sh_xcc, sh_rank;

    const int tid = threadIdx.x;

    // ---- registration: physical XCD id + per-XCD rank ----
    if (tid == 0) {
        unsigned xr;
        asm volatile("s_getreg_b32 %0, hwreg(HW_REG_XCC_ID)" : "=s"(xr));
        xr &= 7u;
        sh_xcc = (int)xr;
        sh_rank = (int)__hip_atomic_fetch_add(ws + 16 + xr, 1u,
                      __ATOMIC_ACQ_REL, __HIP_MEMORY_SCOPE_AGENT);
    }
    __syncthreads();
    const int xcc = sh_xcc, lrank = sh_rank;

    // ---- one-time global barrier (LLC; cost irrelevant, runs once) ----
    if (tid == 0) {
        __hip_atomic_fetch_add(ws, 1u, __ATOMIC_ACQ_REL, __HIP_MEMORY_SCOPE_AGENT);
        int pp = 0;
        while (__hip_atomic_load(ws, __ATOMIC_ACQUIRE, __HIP_MEMORY_SCOPE_AGENT) < NWG) {
            __builtin_amdgcn_s_sleep(8);
            if (++pp > POLL_CAP) break;
        }
    }
    __syncthreads();
    const unsigned mycnt = __hip_atomic_load(ws + 16 + xcc, __ATOMIC_ACQUIRE,
                                             __HIP_MEMORY_SCOPE_AGENT);
    if (mycnt < 32u || lrank >= 32) return;   // replica didn't form / spare WG

    // ---- replica workspace (all within this XCD's L2 working set) ----
    unsigned* const repbase = ws + 1024 + (size_t)xcc * (163840 / 4);
    unsigned* const flags = repbase;               // 32 dense u32
    unsigned* const h0a_  = repbase + 1024;        // each h buf: u32[32][256] = 32 KB
    unsigned* const h0b_  = h0a_ + 8192;
    unsigned* const h1a_  = h0a_ + 16384;
    unsigned* const h1b_  = h0a_ + 24576;

    const int layer = lrank >> 4;          // 0..1
    const int c0    = (lrank & 15) * 32;   // WG's 32 hidden cols
    const int wv    = tid >> 6;
    const int lane  = tid & 63;
    const int i16   = lane & 15;
    const int hi    = lane >> 4;

    // ---- resident weights: A[part(ih/hh)][m-tile][k-tile], 64 frags = 256 VGPR ----
    // m-tile rows: tr<8 -> gate 2m, col c0+wv*8+tr ; tr>=8 -> gate 2m+1, col +tr-8
    bf16x8 A[2][2][16];
    #pragma unroll
    for (int m = 0; m < 2; ++m) {
        const int g   = 2 * m + (i16 >> 3);
        const int row = g * 512 + c0 + wv * 8 + (i16 & 7);
        const float* pih = w_ih + ((size_t)layer * 2048 + row) * 512;
        const float* phh = w_hh + ((size_t)layer * 2048 + row) * 512;
        #pragma unroll
        for (int kt = 0; kt < 16; ++kt) {
            const int k = kt * 32 + hi * 8;
            A[0][m][kt] = cvt8(*(const float4*)(pih + k), *(const float4*)(pih + k + 4));
            A[1][m][kt] = cvt8(*(const float4*)(phh + k), *(const float4*)(phh + k + 4));
        }
    }

    // ---- cell-updater role: thread -> (batch bt, col-quad jp) ----
    const int bt = tid & 31, jp = tid >> 5;
    float biasr[4][4];
    #pragma unroll
    for (int g = 0; g < 4; ++g)
        #pragma unroll
        for (int i = 0; i < 4; ++i) {
            const int c = c0 + jp * 4 + i;
            biasr[g][i] = b_ih[layer * 2048 + g * 512 + c]
                        + b_hh[layer * 2048 + g * 512 + c];
        }
    float cst[4] = {0.f, 0.f, 0.f, 0.f};
    f32x4 acc[2][2];

    short* const inpB = &inp[0][0];

    // stage 512-wide h vector (u32-packed) from replica L2 into LDS
    auto stage_h = [&](const unsigned* hsrc) {
        const int b  = tid >> 3;
        const int j0 = (tid & 7) * 32;
        const unsigned* src = hsrc + b * 256 + j0;
        u32x4 q[8];
        asm volatile(
            "global_load_dwordx4 %0, %4, off sc0\n\t"
            "global_load_dwordx4 %1, %5, off sc0\n\t"
            "global_load_dwordx4 %2, %6, off sc0\n\t"
            "global_load_dwordx4 %3, %7, off sc0\n\t"
            "s_waitcnt vmcnt(0)"
            : "=&v"(q[0]), "=&v"(q[1]), "=&v"(q[2]), "=&v"(q[3])
            : "v"(src), "v"(src + 4), "v"(src + 8), "v"(src + 12)
            : "memory");
        asm volatile(
            "global_load_dwordx4 %0, %4, off sc0\n\t"
            "global_load_dwordx4 %1, %5, off sc0\n\t"
            "global_load_dwordx4 %2, %6, off sc0\n\t"
            "global_load_dwordx4 %3, %7, off sc0\n\t"
            "s_waitcnt vmcnt(0)"
            : "=&v"(q[4]), "=&v"(q[5]), "=&v"(q[6]), "=&v"(q[7])
            : "v"(src + 16), "v"(src + 20), "v"(src + 24), "v"(src + 28)
            : "memory");
        char* dst = (char*)inpB + b * 1040 + j0 * 4;
        #pragma unroll
        for (int i = 0; i < 8; ++i)
            *(u32x4*)(dst + i * 16) = q[i];
    };

    // stage x(tt) = embedding rows, f32 -> bf16, into LDS (plain cached loads)
    auto stage_x = [&](int tt) {
        const int b  = tid >> 3;
        const int k0 = (tid & 7) * 64;
        const float* xr = emb + (size_t)tokens[b * SEQ + tt] * 512 + k0;
        char* dst = (char*)inpB + b * 1040 + k0 * 2;
        #pragma unroll
        for (int i = 0; i < 8; ++i) {
            float4 a = *(const float4*)(xr + i * 8);
            float4 c = *(const float4*)(xr + i * 8 + 4);
            *(bf16x8*)(dst + i * 16) = cvt8(a, c);
        }
    };

#define ZERO_ACC() do { acc[0][0] = f32x4{0.f,0.f,0.f,0.f}; acc[0][1] = f32x4{0.f,0.f,0.f,0.f}; \
                        acc[1][0] = f32x4{0.f,0.f,0.f,0.f}; acc[1][1] = f32x4{0.f,0.f,0.f,0.f}; } while (0)

#define DO_MFMA(P) do { \
    _Pragma("unroll") \
    for (int kt = 0; kt < 16; ++kt) { \
        const char* pb = (const char*)inpB + i16 * 1040 + kt * 64 + hi * 16; \
        bf16x8 B0 = *(const bf16x8*)pb; \
        bf16x8 B1 = *(const bf16x8*)(pb + 16 * 1040); \
        acc[0][0] = __builtin_amdgcn_mfma_f32_16x16x32_bf16(A[P][0][kt], B0, acc[0][0], 0, 0, 0); \
        acc[1][0] = __builtin_amdgcn_mfma_f32_16x16x32_bf16(A[P][1][kt], B0, acc[1][0], 0, 0, 0); \
        acc[0][1] = __builtin_amdgcn_mfma_f32_16x16x32_bf16(A[P][0][kt], B1, acc[0][1], 0, 0, 0); \
        acc[1][1] = __builtin_amdgcn_mfma_f32_16x16x32_bf16(A[P][1][kt], B1, acc[1][1], 0, 0, 0); \
    } } while (0)

    auto write_gbuf = [&]() {
        #pragma unroll
        for (int m = 0; m < 2; ++m)
            #pragma unroll
            for (int nt = 0; nt < 2; ++nt)
                *(f32x4*)&gbuf[2 * m + (hi >> 1)][nt * 16 + i16][wv * 8 + (hi & 1) * 4] = acc[m][nt];
    };

    auto cell_store = [&](unsigned* hout) {
        f32x4 gi = *(f32x4*)&gbuf[0][bt][jp * 4];
        f32x4 gf = *(f32x4*)&gbuf[1][bt][jp * 4];
        f32x4 gg = *(f32x4*)&gbuf[2][bt][jp * 4];
        f32x4 go = *(f32x4*)&gbuf[3][bt][jp * 4];
        float hv[4];
        #pragma unroll
        for (int i = 0; i < 4; ++i) {
            cst[i] = sigf(gf[i] + biasr[1][i]) * cst[i]
                   + sigf(gi[i] + biasr[0][i]) * tanhf_fast(gg[i] + biasr[2][i]);
            hv[i]  = sigf(go[i] + biasr[3][i]) * tanhf_fast(cst[i]);
        }
        u32x2 v; v[0] = pack2(hv[0], hv[1]); v[1] = pack2(hv[2], hv[3]);
        unsigned* hp = hout + bt * 256 + (c0 >> 1) + jp * 2;
        asm volatile("global_store_dwordx2 %0, %1, off sc0" :: "v"(hp), "v"(v) : "memory");
    };

    bool broken = false;
    int polls = 0;

    auto post_flag = [&](unsigned val) {
        if (tid == 0) {
            unsigned* fp = flags + lrank;
            asm volatile("global_store_dword %0, %1, off sc0" :: "v"(fp), "v"(val) : "memory");
        }
    };
    auto poll_flags = [&](unsigned target) {
        if (wv == 0) {
            const unsigned* fp = flags + (lane & 7) * 4;
            for (;;) {
                bool mine = true;
                if (!broken && lane < 8) {
                    u32x4 v = ld_sc0x4(fp);
                    mine = v[0] >= target && v[1] >= target && v[2] >= target && v[3] >= target;
                }
                if (broken || __all(mine)) break;
                __builtin_amdgcn_s_sleep(1);
                if (++polls > POLL_CAP) broken = true;   // bailout: never hang
            }
        }
    };

    // ---- prologue: L0's x(0)-part runs before the loop ----
    ZERO_ACC();
    if (layer == 0) { stage_x(0); __syncthreads(); DO_MFMA(0); }

    for (int k = 0; k <= SEQ; ++k) {
        const int t = layer ? (k - 1) : k;
        const bool active = (t >= 0 && t < SEQ);
        if (active) {
            const int p = t & 1;
            if (layer == 0) {
                stage_h(p ? h0a_ : h0b_);            // h0[t-1]
                __syncthreads();
                DO_MFMA(1);                          // hh part onto x-part acc
                write_gbuf();
                __syncthreads();
                cell_store(p ? h0b_ : h0a_);         // h0[t]
                asm volatile("s_waitcnt vmcnt(0)" ::: "memory");
                if (t + 1 < SEQ) stage_x(t + 1);     // prefetch next x into inp
                __syncthreads();
                post_flag((unsigned)(k + 1));
                if (t + 1 < SEQ) { ZERO_ACC(); DO_MFMA(0); }   // x-part under the wait
                poll_flags((unsigned)(k + 1));
                __syncthreads();
            } else {
                stage_h(p ? h0b_ : h0a_);            // h0[t]
                __syncthreads();
                ZERO_ACC();
                DO_MFMA(0);                          // W_ih1 . h0[t]
                __syncthreads();
                stage_h(p ? h1a_ : h1b_);            // h1[t-1]
                __syncthreads();
                DO_MFMA(1);                          // W_hh1 . h1[t-1]
                write_gbuf();
                __syncthreads();
                cell_store(p ? h1b_ : h1a_);         // h1[t]
                asm volatile("s_waitcnt vmcnt(0)" ::: "memory");
                __syncthreads();
                post_flag((unsigned)(k + 1));
                poll_flags((unsigned)(k + 1));
                __syncthreads();
            }
        } else {
            post_flag((unsigned)(k + 1));
            poll_flags((unsigned)(k + 1));
            __syncthreads();
        }
    }

    // ---- FC head: rank-0 WG of each formed replica (identical outputs race-write) ----
    if (lrank == 0 && tid < 64) {
        const int b = tid >> 1, o = tid & 1;
        float accf = 0.f;
        for (int j = 0; j < 64; ++j) {
            u32x4 u = ld_sc0x4(h1b_ + b * 256 + j * 4);   // t=2047 parity 1 -> h1b
            #pragma unroll
            for (int e = 0; e < 4; ++e) {
                accf += bf2f((unsigned short)(u[e] & 0xFFFFu)) * fc_w[o * HID + j * 8 + e * 2]
                      + bf2f((unsigned short)(u[e] >> 16))     * fc_w[o * HID + j * 8 + e * 2 + 1];
            }
        }
        out[b * 2 + o] = sigf(accf + fc_b[o]);
    }
}

extern "C" void kernel_launch(void* const* d_in, const int* in_sizes, int n_in,
                              void* d_out, int out_size, void* d_ws, size_t ws_size,
                              hipStream_t stream)
{
    const int*   tokens = (const int*)d_in[0];
    const float* emb    = (const float*)d_in[1];
    const float* w_ih   = (const float*)d_in[2];
    const float* w_hh   = (const float*)d_in[3];
    const float* b_ih   = (const float*)d_in[4];
    const float* b_hh   = (const float*)d_in[5];
    const float* fc_w   = (const float*)d_in[6];
    const float* fc_b   = (const float*)d_in[7];

    unsigned* ws = (unsigned*)d_ws;
    // layout: [0] gbar | [16..23] per-XCD rank counters | +4096B: 8 replica areas
    // (160 KB stride: flags 128B @+0, four 32KB h buffers @+4KB)
    hipMemsetAsync(d_ws, 0, 4096 + (size_t)8 * 163840, stream);

    lstm_xcd<<<dim3(NWG), dim3(NTHR), 0, stream>>>(
        tokens, emb, w_ih, w_hh, b_ih, b_hh, fc_w, fc_b,
        (float*)d_out, ws);
}

// Round 8
// 37957.770 us; speedup vs baseline: 21.5819x; 21.5819x over previous
//
#include <hip/hip_runtime.h>

#define SEQ   2048
#define HID   512
#define NB    32
#define NWG   256
#define NTHR  256
#define POLL_CAP 5000000
#define REP_STRIDE (163840 / 4)   // u32 stride between replica areas (160 KB)

typedef __attribute__((ext_vector_type(8))) short bf16x8;
typedef __attribute__((ext_vector_type(4))) float f32x4;
typedef __attribute__((ext_vector_type(4))) unsigned u32x4;
typedef __attribute__((ext_vector_type(2))) unsigned u32x2;

__device__ __forceinline__ float sigf(float x) { return 1.0f / (1.0f + __expf(-x)); }
__device__ __forceinline__ float tanhf_fast(float x) {
    float e = __expf(2.0f * x);
    return (e - 1.0f) / (e + 1.0f);
}
__device__ __forceinline__ short f2bf(float f) {
    unsigned u = __float_as_uint(f);
    unsigned r = (u + 0x7FFFu + ((u >> 16) & 1u)) >> 16;
    return (short)r;
}
__device__ __forceinline__ float bf2f(unsigned short s) {
    return __uint_as_float(((unsigned)s) << 16);
}
__device__ __forceinline__ unsigned pack2(float a, float b) {
    return (unsigned)(unsigned short)f2bf(a) | ((unsigned)(unsigned short)f2bf(b) << 16);
}
__device__ __forceinline__ bf16x8 cvt8(float4 a, float4 b) {
    bf16x8 r;
    r[0] = f2bf(a.x); r[1] = f2bf(a.y); r[2] = f2bf(a.z); r[3] = f2bf(a.w);
    r[4] = f2bf(b.x); r[5] = f2bf(b.y); r[6] = f2bf(b.z); r[7] = f2bf(b.w);
    return r;
}

// PROVEN primitives (rounds 2-6, absmax 0.0): relaxed agent-scope atomics,
// prompt cross-WG visibility, no fence, no L1/L2 maintenance storms.
__device__ __forceinline__ unsigned ld_a(const unsigned* p) {
    return __hip_atomic_load((unsigned*)p, __ATOMIC_RELAXED, __HIP_MEMORY_SCOPE_AGENT);
}
__device__ __forceinline__ void st_a(unsigned* p, unsigned v) {
    __hip_atomic_store(p, v, __ATOMIC_RELAXED, __HIP_MEMORY_SCOPE_AGENT);
}

// XCD-replicated persistent LSTM (R7 structure, R4-proven memory ops).
// 8 replicas (physical XCD via s_getreg HW_REG_XCC_ID), 32 WGs each, every
// replica computes the FULL 2-layer recurrence redundantly. Barriers span
// only the replica's 32 WGs (dense 32-u32 flag block per replica).
// Per WG: 32 hidden cols x 4 gates = 128 gate rows; bf16 weights resident in
// registers (A[2][2][16], 256 regs); 4 waves; MFMA 16x16x32 (proven layout).
__global__ __launch_bounds__(NTHR, 1) void lstm_xcd(
    const int*   __restrict__ tokens, const float* __restrict__ emb,
    const float* __restrict__ w_ih,   const float* __restrict__ w_hh,
    const float* __restrict__ b_ih,   const float* __restrict__ b_hh,
    const float* __restrict__ fc_w,   const float* __restrict__ fc_b,
    float* __restrict__ out, unsigned* __restrict__ ws)
{
    __shared__ __attribute__((aligned(16))) short inp[2][NB][520];  // double-buffered input
    __shared__ __attribute__((aligned(16))) float gbuf[4][NB][36];
    __shared__ int sh_xcc, sh_rank;

    const int tid = threadIdx.x;

    // ---- registration: physical XCD id + per-XCD rank ----
    if (tid == 0) {
        unsigned xr;
        asm volatile("s_getreg_b32 %0, hwreg(HW_REG_XCC_ID)" : "=s"(xr));
        xr &= 7u;
        sh_xcc = (int)xr;
        sh_rank = (int)__hip_atomic_fetch_add(ws + 16 + xr, 1u,
                      __ATOMIC_ACQ_REL, __HIP_MEMORY_SCOPE_AGENT);
    }
    __syncthreads();
    const int xcc = sh_xcc, lrank = sh_rank;

    // ---- one-time global barrier (runs once; cost irrelevant) ----
    if (tid == 0) {
        __hip_atomic_fetch_add(ws, 1u, __ATOMIC_ACQ_REL, __HIP_MEMORY_SCOPE_AGENT);
        int pp = 0;
        while (__hip_atomic_load(ws, __ATOMIC_ACQUIRE, __HIP_MEMORY_SCOPE_AGENT) < NWG) {
            __builtin_amdgcn_s_sleep(8);
            if (++pp > POLL_CAP) break;
        }
    }
    __syncthreads();
    const unsigned mycnt = __hip_atomic_load(ws + 16 + xcc, __ATOMIC_ACQUIRE,
                                             __HIP_MEMORY_SCOPE_AGENT);
    if (mycnt < 32u || lrank >= 32) return;   // replica didn't form / spare WG

    // ---- replica workspace ----
    unsigned* const repbase = ws + 1024 + (size_t)xcc * REP_STRIDE;
    unsigned* const flags = repbase;               // 32 dense u32 (2 lines)
    unsigned* const h0a_  = repbase + 1024;        // each h buf: u32[32][256] = 32 KB
    unsigned* const h0b_  = h0a_ + 8192;
    unsigned* const h1a_  = h0a_ + 16384;
    unsigned* const h1b_  = h0a_ + 24576;

    const int layer = lrank >> 4;          // 0..1
    const int c0    = (lrank & 15) * 32;   // WG's 32 hidden cols
    const int wv    = tid >> 6;
    const int lane  = tid & 63;
    const int i16   = lane & 15;
    const int hi    = lane >> 4;

    // ---- resident weights: A[part(ih/hh)][m-tile][k-tile] ----
    bf16x8 A[2][2][16];
    #pragma unroll
    for (int m = 0; m < 2; ++m) {
        const int g   = 2 * m + (i16 >> 3);
        const int row = g * 512 + c0 + wv * 8 + (i16 & 7);
        const float* pih = w_ih + ((size_t)layer * 2048 + row) * 512;
        const float* phh = w_hh + ((size_t)layer * 2048 + row) * 512;
        #pragma unroll
        for (int kt = 0; kt < 16; ++kt) {
            const int k = kt * 32 + hi * 8;
            A[0][m][kt] = cvt8(*(const float4*)(pih + k), *(const float4*)(pih + k + 4));
            A[1][m][kt] = cvt8(*(const float4*)(phh + k), *(const float4*)(phh + k + 4));
        }
    }

    // ---- cell-updater role: thread -> (batch bt, col-quad jp) ----
    const int bt = tid & 31, jp = tid >> 5;
    float biasr[4][4];
    #pragma unroll
    for (int g = 0; g < 4; ++g)
        #pragma unroll
        for (int i = 0; i < 4; ++i) {
            const int c = c0 + jp * 4 + i;
            biasr[g][i] = b_ih[layer * 2048 + g * 512 + c]
                        + b_hh[layer * 2048 + g * 512 + c];
        }
    float cst[4] = {0.f, 0.f, 0.f, 0.f};
    f32x4 acc[2][2];

    short* const inpB = &inp[0][0][0];

    // stage 512-wide h vector (u32-packed) into LDS buffer sel, via atomic loads
    auto stage_h = [&](const unsigned* hsrc, int sel) {
        const int b  = tid >> 3;
        const int j0 = (tid & 7) * 32;
        const unsigned* src = hsrc + b * 256 + j0;
        unsigned q[32];
        #pragma unroll
        for (int i = 0; i < 32; ++i) q[i] = ld_a(src + i);
        char* dst = (char*)inpB + sel * 33280 + b * 1040 + j0 * 4;
        #pragma unroll
        for (int i = 0; i < 8; ++i) {
            u32x4 v = {q[4 * i], q[4 * i + 1], q[4 * i + 2], q[4 * i + 3]};
            *(u32x4*)(dst + i * 16) = v;
        }
    };

    // stage x(tt) = embedding rows, f32 -> bf16, into buffer 0 (plain cached loads)
    auto stage_x = [&](int tt) {
        const int b  = tid >> 3;
        const int k0 = (tid & 7) * 64;
        const float* xr = emb + (size_t)tokens[b * SEQ + tt] * 512 + k0;
        char* dst = (char*)inpB + b * 1040 + k0 * 2;
        #pragma unroll
        for (int i = 0; i < 8; ++i) {
            float4 a = *(const float4*)(xr + i * 8);
            float4 c = *(const float4*)(xr + i * 8 + 4);
            *(bf16x8*)(dst + i * 16) = cvt8(a, c);
        }
    };

#define ZERO_ACC() do { acc[0][0] = f32x4{0.f,0.f,0.f,0.f}; acc[0][1] = f32x4{0.f,0.f,0.f,0.f}; \
                        acc[1][0] = f32x4{0.f,0.f,0.f,0.f}; acc[1][1] = f32x4{0.f,0.f,0.f,0.f}; } while (0)

#define DO_MFMA(P, SEL) do { \
    _Pragma("unroll") \
    for (int kt = 0; kt < 16; ++kt) { \
        const char* pb = (const char*)inpB + (SEL) * 33280 + i16 * 1040 + kt * 64 + hi * 16; \
        bf16x8 B0 = *(const bf16x8*)pb; \
        bf16x8 B1 = *(const bf16x8*)(pb + 16 * 1040); \
        acc[0][0] = __builtin_amdgcn_mfma_f32_16x16x32_bf16(A[P][0][kt], B0, acc[0][0], 0, 0, 0); \
        acc[1][0] = __builtin_amdgcn_mfma_f32_16x16x32_bf16(A[P][1][kt], B0, acc[1][0], 0, 0, 0); \
        acc[0][1] = __builtin_amdgcn_mfma_f32_16x16x32_bf16(A[P][0][kt], B1, acc[0][1], 0, 0, 0); \
        acc[1][1] = __builtin_amdgcn_mfma_f32_16x16x32_bf16(A[P][1][kt], B1, acc[1][1], 0, 0, 0); \
    } } while (0)

    auto write_gbuf = [&]() {
        #pragma unroll
        for (int m = 0; m < 2; ++m)
            #pragma unroll
            for (int nt = 0; nt < 2; ++nt)
                *(f32x4*)&gbuf[2 * m + (hi >> 1)][nt * 16 + i16][wv * 8 + (hi & 1) * 4] = acc[m][nt];
    };

    auto cell_store = [&](unsigned* hout) {
        f32x4 gi = *(f32x4*)&gbuf[0][bt][jp * 4];
        f32x4 gf = *(f32x4*)&gbuf[1][bt][jp * 4];
        f32x4 gg = *(f32x4*)&gbuf[2][bt][jp * 4];
        f32x4 go = *(f32x4*)&gbuf[3][bt][jp * 4];
        float hv[4];
        #pragma unroll
        for (int i = 0; i < 4; ++i) {
            cst[i] = sigf(gf[i] + biasr[1][i]) * cst[i]
                   + sigf(gi[i] + biasr[0][i]) * tanhf_fast(gg[i] + biasr[2][i]);
            hv[i]  = sigf(go[i] + biasr[3][i]) * tanhf_fast(cst[i]);
        }
        unsigned* hp = hout + bt * 256 + (c0 >> 1) + jp * 2;
        st_a(hp + 0, pack2(hv[0], hv[1]));
        st_a(hp + 1, pack2(hv[2], hv[3]));
    };

    bool broken = false;
    int polls = 0;

    auto post_flag = [&](unsigned val) {
        if (tid == 0) st_a(flags + lrank, val);
    };
    // single-hop sweep: lanes 0-31 of wave 0 each watch one dense flag (2 lines)
    auto poll_flags = [&](unsigned target) {
        if (wv == 0) {
            for (;;) {
                bool mine = true;
                if (!broken && lane < 32) mine = (ld_a(flags + lane) >= target);
                if (broken || __all(mine)) break;
                __builtin_amdgcn_s_sleep(2);
                if (++polls > POLL_CAP) broken = true;   // bailout: never hang
            }
        }
    };

    // ---- prologue: L0's x(0)-part before the loop ----
    ZERO_ACC();
    if (layer == 0) { stage_x(0); __syncthreads(); DO_MFMA(0, 0); }

    for (int k = 0; k <= SEQ; ++k) {
        const int t = layer ? (k - 1) : k;
        const bool active = (t >= 0 && t < SEQ);
        if (active) {
            const int p = t & 1;
            if (layer == 0) {
                stage_h(p ? h0a_ : h0b_, 1);          // h0[t-1] -> buf1
                __syncthreads();
                DO_MFMA(1, 1);                         // hh-part onto resident x-part acc
                write_gbuf();
                __syncthreads();
                cell_store(p ? h0b_ : h0a_);           // h0[t]
                asm volatile("s_waitcnt vmcnt(0)" ::: "memory");  // per-wave drain
                if (t + 1 < SEQ) stage_x(t + 1);       // prefetch next x -> buf0
                __syncthreads();                       // all waves' h stores done
                post_flag((unsigned)(k + 1));
                if (t + 1 < SEQ) { ZERO_ACC(); DO_MFMA(0, 0); }  // x-part under the wait
                poll_flags((unsigned)(k + 1));
                __syncthreads();
            } else {
                stage_h(p ? h0b_ : h0a_, 0);           // h0[t]   -> buf0
                stage_h(p ? h1a_ : h1b_, 1);           // h1[t-1] -> buf1 (loads overlap)
                __syncthreads();
                ZERO_ACC();
                DO_MFMA(0, 0);                         // W_ih1 . h0[t]
                DO_MFMA(1, 1);                         // W_hh1 . h1[t-1]
                write_gbuf();
                __syncthreads();
                cell_store(p ? h1b_ : h1a_);           // h1[t]
                asm volatile("s_waitcnt vmcnt(0)" ::: "memory");
                __syncthreads();
                post_flag((unsigned)(k + 1));
                poll_flags((unsigned)(k + 1));
                __syncthreads();
            }
        } else {
            post_flag((unsigned)(k + 1));
            poll_flags((unsigned)(k + 1));
            __syncthreads();
        }
    }

    // ---- FC head: rank-0 WG of each formed replica (identical outputs) ----
    if (lrank == 0 && tid < 64) {
        const int b = tid >> 1, o = tid & 1;
        float accf = 0.f;
        for (int j2 = 0; j2 < 256; ++j2) {
            unsigned u = ld_a(h1b_ + b * 256 + j2);    // t=2047 parity 1 -> h1b
            accf += bf2f((unsigned short)(u & 0xFFFFu)) * fc_w[o * HID + 2 * j2]
                  + bf2f((unsigned short)(u >> 16))     * fc_w[o * HID + 2 * j2 + 1];
        }
        out[b * 2 + o] = sigf(accf + fc_b[o]);
    }
}

extern "C" void kernel_launch(void* const* d_in, const int* in_sizes, int n_in,
                              void* d_out, int out_size, void* d_ws, size_t ws_size,
                              hipStream_t stream)
{
    const int*   tokens = (const int*)d_in[0];
    const float* emb    = (const float*)d_in[1];
    const float* w_ih   = (const float*)d_in[2];
    const float* w_hh   = (const float*)d_in[3];
    const float* b_ih   = (const float*)d_in[4];
    const float* b_hh   = (const float*)d_in[5];
    const float* fc_w   = (const float*)d_in[6];
    const float* fc_b   = (const float*)d_in[7];

    unsigned* ws = (unsigned*)d_ws;
    // layout: [0] gbar | [16..23] per-XCD rank counters | +4096B: 8 replica areas
    // (160 KB stride: 32 flags @+0, four 32KB h buffers @+4KB)
    hipMemsetAsync(d_ws, 0, 4096 + (size_t)8 * 163840, stream);

    lstm_xcd<<<dim3(NWG), dim3(NTHR), 0, stream>>>(
        tokens, emb, w_ih, w_hh, b_ih, b_hh, fc_w, fc_b,
        (float*)d_out, ws);
}